// Round 2
// baseline (4714.240 us; speedup 1.0000x reference)
//
#include <hip/hip_runtime.h>
#include <hip/hip_bf16.h>
#include <math.h>

#define BB 16
#define SS 4096
#define DD 1024
#define MMd 512
#define BSr (BB*SS)   // 65536 rows

// ---------------------------------------------------------------------------
// QKV projection: fp32 tiled GEMM.  C[r, n] = x[r,:] . W[n,:] + bias[n]
// 1-D grid 6144, swizzled so the 12 column-tiles (q/k/v x 4) of one x-row-tile
// are temporally consecutive on the SAME XCD (f mod 8 = by mod 8).
// Tile 128x128, BK=16, 256 threads, 8x8 micro-tile per thread.
// ---------------------------------------------------------------------------
__global__ __launch_bounds__(256) void qkv_gemm(
    const float* __restrict__ x,
    const float* __restrict__ Wq, const float* __restrict__ bq,
    const float* __restrict__ Wk, const float* __restrict__ bk,
    const float* __restrict__ Wv, const float* __restrict__ bv,
    float* __restrict__ qo, float* __restrict__ ko, float* __restrict__ vo)
{
    const int f   = blockIdx.x;
    const int r96 = f % 96;
    const int by  = ((f / 96) << 3) | (r96 & 7);   // 0..511 row tile
    const int bx  = r96 >> 3;                      // 0..11 col tile
    const int tid = threadIdx.x;

    const int r0  = by * 128;
    const int arr = bx >> 2;               // 0=q 1=k 2=v
    const int colbase = (bx & 3) * 128;    // column offset within 512

    const float* W    = (arr == 0) ? Wq : (arr == 1) ? Wk : Wv;
    const float* bias = (arr == 0) ? bq : (arr == 1) ? bk : bv;
    float* dst        = (arr == 0) ? qo : (arr == 1) ? ko : vo;

    __shared__ float As[16][128];
    __shared__ float Bs[16][128];

    const int tr = tid >> 4;      // 0..15 (rows)
    const int tc = tid & 15;      // 0..15 (cols)

    // staging: slot = (m, kquad); thread does slots tid and tid+256
    const int sm0 = tid >> 2;           // 0..63
    const int sm1 = sm0 + 64;           // 64..127
    const int skq = (tid & 3) * 4;      // k offset 0,4,8,12

    const float* xa0 = x + (size_t)(r0 + sm0) * DD + skq;
    const float* xa1 = x + (size_t)(r0 + sm1) * DD + skq;
    const float* wb0 = W + (size_t)(colbase + sm0) * DD + skq;
    const float* wb1 = W + (size_t)(colbase + sm1) * DD + skq;

    float4 a0 = *(const float4*)xa0;
    float4 a1 = *(const float4*)xa1;
    float4 b0 = *(const float4*)wb0;
    float4 b1 = *(const float4*)wb1;

    float acc[8][8];
    #pragma unroll
    for (int i = 0; i < 8; ++i)
        #pragma unroll
        for (int j = 0; j < 8; ++j) acc[i][j] = 0.f;

    for (int kt = 0; kt < 64; ++kt) {
        __syncthreads();
        As[skq+0][sm0]=a0.x; As[skq+1][sm0]=a0.y; As[skq+2][sm0]=a0.z; As[skq+3][sm0]=a0.w;
        As[skq+0][sm1]=a1.x; As[skq+1][sm1]=a1.y; As[skq+2][sm1]=a1.z; As[skq+3][sm1]=a1.w;
        Bs[skq+0][sm0]=b0.x; Bs[skq+1][sm0]=b0.y; Bs[skq+2][sm0]=b0.z; Bs[skq+3][sm0]=b0.w;
        Bs[skq+0][sm1]=b1.x; Bs[skq+1][sm1]=b1.y; Bs[skq+2][sm1]=b1.z; Bs[skq+3][sm1]=b1.w;
        __syncthreads();

        if (kt < 63) {                        // prefetch next K-tile
            const int k0 = (kt + 1) * 16;
            a0 = *(const float4*)(xa0 + k0);
            a1 = *(const float4*)(xa1 + k0);
            b0 = *(const float4*)(wb0 + k0);
            b1 = *(const float4*)(wb1 + k0);
        }

        #pragma unroll
        for (int kk = 0; kk < 16; ++kk) {
            float4 af0 = *(const float4*)&As[kk][tr*8];
            float4 af1 = *(const float4*)&As[kk][tr*8+4];
            float4 bf0 = *(const float4*)&Bs[kk][tc*8];
            float4 bf1 = *(const float4*)&Bs[kk][tc*8+4];
            float av[8] = {af0.x,af0.y,af0.z,af0.w,af1.x,af1.y,af1.z,af1.w};
            float bw[8] = {bf0.x,bf0.y,bf0.z,bf0.w,bf1.x,bf1.y,bf1.z,bf1.w};
            #pragma unroll
            for (int i = 0; i < 8; ++i)
                #pragma unroll
                for (int j = 0; j < 8; ++j)
                    acc[i][j] = fmaf(av[i], bw[j], acc[i][j]);
        }
    }

    const float4 bias0 = *(const float4*)(bias + colbase + tc*8);
    const float4 bias1 = *(const float4*)(bias + colbase + tc*8 + 4);
    #pragma unroll
    for (int i = 0; i < 8; ++i) {
        const size_t row = (size_t)(r0 + tr*8 + i);
        float4 o0, o1;
        o0.x = acc[i][0]+bias0.x; o0.y = acc[i][1]+bias0.y;
        o0.z = acc[i][2]+bias0.z; o0.w = acc[i][3]+bias0.w;
        o1.x = acc[i][4]+bias1.x; o1.y = acc[i][5]+bias1.y;
        o1.z = acc[i][6]+bias1.z; o1.w = acc[i][7]+bias1.w;
        *(float4*)(dst + row*MMd + colbase + tc*8)     = o0;
        *(float4*)(dst + row*MMd + colbase + tc*8 + 4) = o1;
    }
}

// ---------------------------------------------------------------------------
// Scan: persistent, Mem register-resident, TWO time steps per barrier pair.
// grid 256: blk = cg*16 + b  (so all 16 blocks of batch b share an XCD)
// 256 threads: c4 = tid&7 (column quad: 4 cols), g = tid>>3 (m-group: 16 rows)
// Mem slice per thread: Mreg[16] (float4 over its 4 columns).
// Rescaled accumulator: Mem_true = scale * Macc ; fold every 32 steps.
// ---------------------------------------------------------------------------
__global__ __launch_bounds__(256) void scan_kernel(
    const float* __restrict__ q, const float* __restrict__ k,
    const float* __restrict__ v, const float* __restrict__ alpha_p,
    float* __restrict__ out, float* __restrict__ memf)
{
    const int blk = blockIdx.x;
    const int b   = blk & 15;           // batch  (blk ≡ b mod 8 → same XCD)
    const int cg  = blk >> 4;           // column group 0..15
    const int tid = threadIdx.x;
    const int c4  = tid & 7;
    const int g   = tid >> 3;           // 0..31

    const float alpha   = *alpha_p;
    const float a       = 1.f / (1.f + expf(-alpha));
    const float oma     = 1.f - a;
    const float inv_oma = 1.f / oma;

    // q/k broadcast buffers, padded: group g lives at [g*20, g*20+16)
    __shared__ float qlds[2][640];
    __shared__ float klds[2][640];
    __shared__ float rpart[2][32][36];  // [step][col][g], 16B-aligned rows

    float4 Mreg[16];
    #pragma unroll
    for (int i = 0; i < 16; ++i) Mreg[i] = make_float4(0.f,0.f,0.f,0.f);

    const int stageIdx = 2*tid + ((tid>>3)<<2);   // phys idx for m=2*tid
    const size_t rowbase = (size_t)b * SS * MMd;
    const int vcol = cg*32 + c4*4;
    const int qb   = g*20;

    const float* qrow = q + rowbase;
    const float* krow = k + rowbase;
    const float* vrow = v + rowbase;

    float2 qv0 = *(const float2*)(qrow + 2*tid);
    float2 kv0 = *(const float2*)(krow + 2*tid);
    float4 vv0 = *(const float4*)(vrow + vcol);
    float2 qv1 = *(const float2*)(qrow + MMd + 2*tid);
    float2 kv1 = *(const float2*)(krow + MMd + 2*tid);
    float4 vv1 = *(const float4*)(vrow + MMd + vcol);

    float scale = 1.f, invs = 1.f;

    const int col = tid >> 3;   // 0..31 (reduction role)
    const int oct = tid & 7;

    for (int t = 0; t < SS; t += 2) {
        const float osA  = scale;            // Mem_true scale before step t
        const float osB  = scale * oma;      // before step t+1
        const float ksfA = a * invs * inv_oma;
        const float ksfB = ksfA * inv_oma;
        scale = osB * oma;
        invs  = invs * inv_oma * inv_oma;

        *(float2*)&qlds[0][stageIdx] = qv0;
        *(float2*)&klds[0][stageIdx] = make_float2(kv0.x*ksfA, kv0.y*ksfA);
        *(float2*)&qlds[1][stageIdx] = qv1;
        *(float2*)&klds[1][stageIdx] = make_float2(kv1.x*ksfB, kv1.y*ksfB);
        const float4 vA = vv0;
        const float4 vB = vv1;
        __syncthreads();                              // LDS staged

        if (t + 2 < SS) {                             // prefetch next 2 steps
            const size_t o0 = (size_t)(t+2) * MMd;
            const size_t o1 = (size_t)(t+3) * MMd;
            qv0 = *(const float2*)(qrow + o0 + 2*tid);
            kv0 = *(const float2*)(krow + o0 + 2*tid);
            vv0 = *(const float4*)(vrow + o0 + vcol);
            qv1 = *(const float2*)(qrow + o1 + 2*tid);
            kv1 = *(const float2*)(krow + o1 + 2*tid);
            vv1 = *(const float4*)(vrow + o1 + vcol);
        }

#define SCAN_STEP(mi, qs, ks, VC)                          \
        racc.x = fmaf(qs, Mreg[mi].x, racc.x);             \
        racc.y = fmaf(qs, Mreg[mi].y, racc.y);             \
        racc.z = fmaf(qs, Mreg[mi].z, racc.z);             \
        racc.w = fmaf(qs, Mreg[mi].w, racc.w);             \
        Mreg[mi].x = fmaf(ks, VC.x, Mreg[mi].x);           \
        Mreg[mi].y = fmaf(ks, VC.y, Mreg[mi].y);           \
        Mreg[mi].z = fmaf(ks, VC.z, Mreg[mi].z);           \
        Mreg[mi].w = fmaf(ks, VC.w, Mreg[mi].w);

#define COMPUTE_STEP(S, VC)                                        \
        {                                                          \
            float4 racc = make_float4(0.f,0.f,0.f,0.f);            \
            _Pragma("unroll")                                      \
            for (int j = 0; j < 4; ++j) {                          \
                const float4 q4 = *(const float4*)&qlds[S][qb + j*4]; \
                const float4 k4 = *(const float4*)&klds[S][qb + j*4]; \
                SCAN_STEP(j*4+0, q4.x, k4.x, VC)                   \
                SCAN_STEP(j*4+1, q4.y, k4.y, VC)                   \
                SCAN_STEP(j*4+2, q4.z, k4.z, VC)                   \
                SCAN_STEP(j*4+3, q4.w, k4.w, VC)                   \
            }                                                      \
            rpart[S][c4*4+0][g] = racc.x;                          \
            rpart[S][c4*4+1][g] = racc.y;                          \
            rpart[S][c4*4+2][g] = racc.z;                          \
            rpart[S][c4*4+3][g] = racc.w;                          \
        }

        COMPUTE_STEP(0, vA)
        COMPUTE_STEP(1, vB)
#undef COMPUTE_STEP
#undef SCAN_STEP

        __syncthreads();                              // partials ready

        {
            const float4 p0 = *(const float4*)&rpart[0][col][oct*4];
            float s0 = (p0.x + p0.y) + (p0.z + p0.w);
            s0 += __shfl_xor(s0, 1);
            s0 += __shfl_xor(s0, 2);
            s0 += __shfl_xor(s0, 4);
            const float4 p1 = *(const float4*)&rpart[1][col][oct*4];
            float s1 = (p1.x + p1.y) + (p1.z + p1.w);
            s1 += __shfl_xor(s1, 1);
            s1 += __shfl_xor(s1, 2);
            s1 += __shfl_xor(s1, 4);
            if (oct == 0) {
                out[rowbase + (size_t)t     * MMd + cg*32 + col] = osA * s0;
                out[rowbase + (size_t)(t+1) * MMd + cg*32 + col] = osB * s1;
            }
        }

        if ((t & 31) == 30) {                         // fold scale into Macc
            #pragma unroll
            for (int i = 0; i < 16; ++i) {
                Mreg[i].x *= scale; Mreg[i].y *= scale;
                Mreg[i].z *= scale; Mreg[i].w *= scale;
            }
            scale = 1.f; invs = 1.f;
        }
    }

    // final memory state (scale == 1 after the t=4095 fold)
    float* mf = memf + (size_t)b * MMd * MMd;
    #pragma unroll
    for (int i = 0; i < 16; ++i)
        *(float4*)(mf + (size_t)(g*16 + i) * MMd + vcol) = Mreg[i];
}

// ---------------------------------------------------------------------------
extern "C" void kernel_launch(void* const* d_in, const int* in_sizes, int n_in,
                              void* d_out, int out_size, void* d_ws, size_t ws_size,
                              hipStream_t stream)
{
    const float* x  = (const float*)d_in[0];
    const float* Wq = (const float*)d_in[1];
    const float* bq = (const float*)d_in[2];
    const float* Wk = (const float*)d_in[3];
    const float* bk = (const float*)d_in[4];
    const float* Wv = (const float*)d_in[5];
    const float* bv = (const float*)d_in[6];
    const float* al = (const float*)d_in[7];

    float* ws = (float*)d_ws;
    float* q = ws;
    float* k = ws + (size_t)BSr * MMd;
    float* v = ws + 2 * (size_t)BSr * MMd;

    float* out  = (float*)d_out;
    float* memf = out + (size_t)BB * SS * MMd;

    qkv_gemm<<<6144, 256, 0, stream>>>(x, Wq, bq, Wk, bk, Wv, bv, q, k, v);
    scan_kernel<<<256, 256, 0, stream>>>(q, k, v, al, out, memf);
}

// Round 4
// 1264.670 us; speedup vs baseline: 3.7276x; 3.7276x over previous
//
#include <hip/hip_runtime.h>
#include <hip/hip_bf16.h>
#include <math.h>

#define BB 16
#define SS 4096
#define DD 1024
#define MMd 512

typedef __attribute__((ext_vector_type(8))) short short8;
typedef __attribute__((ext_vector_type(4))) float f32x4;
typedef __attribute__((ext_vector_type(4))) unsigned short us4;
typedef __attribute__((ext_vector_type(4))) unsigned int ui4;

__device__ __forceinline__ float bf2f(short s) {
    unsigned int u = ((unsigned int)(unsigned short)s) << 16;
    return __builtin_bit_cast(float, u);
}
__device__ __forceinline__ short f2bf(float f) {
    unsigned int u = __builtin_bit_cast(unsigned int, f);
    u = (u + 0x7FFFu + ((u >> 16) & 1u)) >> 16;
    return (short)u;
}
// exact small integer power (error <= n ulp; __powf would break decay cancellation)
__device__ __forceinline__ float powi(float x, int n) {
    float p = 1.f;
    for (int e = 0; e < n; ++e) p *= x;
    return p;
}
#define MFMA16(a, b, c) __builtin_amdgcn_mfma_f32_16x16x32_bf16(a, b, c, 0, 0, 0)

__device__ __forceinline__ void gload_lds16(const void* g, void* l) {
    __builtin_amdgcn_global_load_lds(
        (const __attribute__((address_space(1))) unsigned int*)g,
        (__attribute__((address_space(3))) unsigned int*)l, 16, 0, 0);
}

// ---------------------------------------------------------------------------
// fp32 -> bf16 conversion: x (67.1M elems) and Wq|Wk|Wv (1.57M elems)
// ---------------------------------------------------------------------------
__global__ __launch_bounds__(256) void to_bf16(
    const float* __restrict__ x, const float* __restrict__ Wq,
    const float* __restrict__ Wk, const float* __restrict__ Wv,
    unsigned short* __restrict__ xb, unsigned short* __restrict__ wb)
{
    size_t blk = blockIdx.x;
    const float* src;
    unsigned short* dst;
    size_t off;
    if (blk < 32768) {
        off = (blk * 256 + threadIdx.x) * 8;
        src = x; dst = xb;
    } else {
        off = ((blk - 32768) * 256 + threadIdx.x) * 8;   // 0..1572863
        size_t which = off >> 19;                         // /524288
        src = (which == 0) ? Wq : (which == 1) ? Wk : Wv;
        src -= which << 19;                               // so src[off] indexes right array
        dst = wb;
    }
    float4 f0 = *(const float4*)(src + off);
    float4 f1 = *(const float4*)(src + off + 4);
    unsigned int p[4];
    p[0] = ((unsigned int)(unsigned short)f2bf(f0.y) << 16) | (unsigned short)f2bf(f0.x);
    p[1] = ((unsigned int)(unsigned short)f2bf(f0.w) << 16) | (unsigned short)f2bf(f0.z);
    p[2] = ((unsigned int)(unsigned short)f2bf(f1.y) << 16) | (unsigned short)f2bf(f1.x);
    p[3] = ((unsigned int)(unsigned short)f2bf(f1.w) << 16) | (unsigned short)f2bf(f1.z);
    *(ui4*)(dst + off) = *(ui4*)p;
}

// ---------------------------------------------------------------------------
// QKV projection, bf16 MFMA (m97-style): C[r][n] = xb[r,:].wb[n,:] + bias[n]
// 128x128 tile, BK=32, 4 waves (each 64x64 quadrant, 4x4 tiles of 16x16).
// Writes q/k/v bf16 and (for k) a transposed copy kT[b][m][s].
// ---------------------------------------------------------------------------
__global__ __launch_bounds__(256, 2) void qkv_gemm(
    const unsigned short* __restrict__ xb, const unsigned short* __restrict__ wb,
    const float* __restrict__ bq, const float* __restrict__ bk, const float* __restrict__ bv,
    unsigned short* __restrict__ qo, unsigned short* __restrict__ ko,
    unsigned short* __restrict__ vo, unsigned short* __restrict__ kT)
{
    __shared__ unsigned short As[128 * 32];
    __shared__ unsigned short Bs[128 * 32];

    const int f   = blockIdx.x;
    const int r96 = f % 96;
    const int by  = ((f / 96) << 3) | (r96 & 7);   // 0..511 row tile (XCD-stable)
    const int bx  = r96 >> 3;                      // 0..11 col tile
    const int tid = threadIdx.x;
    const int l   = tid & 63, w = tid >> 6;
    const int l15 = l & 15, lg = l >> 4;
    const int wr  = w >> 1, wc = w & 1;
    const size_t r0 = (size_t)by * 128;
    const int nrow0 = bx * 128;                    // wb row base

    // staging addresses (call c stages rows c*64 + tid>>2, k-offset (tid&3)*8)
    const unsigned short* ga  = xb + (r0 + (tid >> 2)) * DD + (tid & 3) * 8;
    const unsigned short* ga2 = ga + (size_t)64 * DD;
    const unsigned short* gb  = wb + (size_t)(nrow0 + (tid >> 2)) * DD + (tid & 3) * 8;
    const unsigned short* gb2 = gb + (size_t)64 * DD;

    f32x4 acc[4][4];
    #pragma unroll
    for (int i = 0; i < 4; ++i)
        #pragma unroll
        for (int j = 0; j < 4; ++j) acc[i][j] = (f32x4){0.f, 0.f, 0.f, 0.f};

    for (int kt = 0; kt < 32; ++kt) {
        __syncthreads();
        gload_lds16(ga  + kt * 32, &As[(size_t)(w * 64) * 8]);
        gload_lds16(ga2 + kt * 32, &As[(size_t)(256 + w * 64) * 8]);
        gload_lds16(gb  + kt * 32, &Bs[(size_t)(w * 64) * 8]);
        gload_lds16(gb2 + kt * 32, &Bs[(size_t)(256 + w * 64) * 8]);
        __syncthreads();

        short8 Af[4], Bf[4];
        #pragma unroll
        for (int t4 = 0; t4 < 4; ++t4) {
            Af[t4] = *(const short8*)&As[(l15 + t4 * 16 + wr * 64) * 32 + lg * 8];
            Bf[t4] = *(const short8*)&Bs[(l15 + t4 * 16 + wc * 64) * 32 + lg * 8];
        }
        #pragma unroll
        for (int ti = 0; ti < 4; ++ti)
            #pragma unroll
            for (int tj = 0; tj < 4; ++tj)
                acc[ti][tj] = MFMA16(Af[ti], Bf[tj], acc[ti][tj]);
    }

    const int arr  = bx >> 2;              // 0=q 1=k 2=v
    const int col0 = (bx & 3) * 128;
    const float* bias   = (arr == 0) ? bq : (arr == 1) ? bk : bv;
    unsigned short* dst = (arr == 0) ? qo : (arr == 1) ? ko : vo;
    const int bI = by >> 5;                // batch
    const int sB = (by & 31) * 128;        // s base within batch

    #pragma unroll
    for (int tj = 0; tj < 4; ++tj) {
        const int jg = col0 + wc * 64 + tj * 16 + l15;
        const float bb = bias[jg];
        #pragma unroll
        for (int ti = 0; ti < 4; ++ti) {
            const int rl = wr * 64 + ti * 16 + lg * 4;
            us4 pk;
            #pragma unroll
            for (int r = 0; r < 4; ++r) {
                unsigned short h = (unsigned short)f2bf(acc[ti][tj][r] + bb);
                dst[(r0 + rl + r) * MMd + jg] = h;
                pk[r] = h;
            }
            if (arr == 1)
                *(us4*)&kT[((size_t)bI * MMd + jg) * SS + (sB + rl)] = pk;
        }
    }
}

// ---------------------------------------------------------------------------
// Chunked scan, MFMA. 256 blocks: blk = cg*16 + b (batch b XCD-colocated).
// Block owns (b, cols n0..n0+31). M (512x32) fp32 in regs (C/D layout,
// transposed: Mt[n][m]). Chunk C=32, 128 chunks, 4 barriers per chunk.
//   r_i = (1-a)^i (q_i.M0) + sum_{j<i} a(1-a)^{i-1-j}(q_i.k_j) v_j
//   M  <- (1-a)^32 M + K^T Vtil,  Vtil_j = a(1-a)^{31-j} v_j
// ---------------------------------------------------------------------------
__global__ __launch_bounds__(256, 1) void scan_mfma(
    const unsigned short* __restrict__ qg, const unsigned short* __restrict__ kg,
    const unsigned short* __restrict__ vg, const unsigned short* __restrict__ kTg,
    const float* __restrict__ alpha_p, float* __restrict__ out, float* __restrict__ memf)
{
    const int blk = blockIdx.x;
    const int b = blk & 15, cg = blk >> 4;
    const int n0 = cg * 32;
    const int tid = threadIdx.x, l = tid & 63, w = tid >> 6;
    const int l15 = l & 15, lg = l >> 4;

    const float alpha = *alpha_p;
    const float a   = 1.f / (1.f + __expf(-alpha));
    const float oma = 1.f - a;

    __shared__ unsigned short Mb[32 * 520];   // [n][512+8], XOR-swizzled cols
    __shared__ unsigned short Vt[32 * 40];    // Vtil^T [n][j]
    __shared__ unsigned short Sl[32 * 40];    // S' [i][j]
    __shared__ float P[4][32][36];            // partial exchange
    __shared__ float P2[32][36];              // intra-tile contribution

    f32x4 Macc[2][8];
    #pragma unroll
    for (int tn = 0; tn < 2; ++tn)
        #pragma unroll
        for (int tm = 0; tm < 8; ++tm) Macc[tn][tm] = (f32x4){0.f, 0.f, 0.f, 0.f};

    // exact decay constants (repeated multiply, not __powf: cancellation-safe)
    float o2 = oma * oma, o4 = o2 * o2, o8 = o4 * o4, o16 = o8 * o8;
    const float dC = o16 * o16;                    // (1-a)^32
    const int vj = tid >> 3, vn = (tid & 7) * 4;   // V-stage role
    const float dkj = a * powi(oma, 31 - vj);      // a(1-a)^{31-j}
    const int ri = tid >> 3, rn = (tid & 7) * 4;   // reduce role
    const float powo_ri = powi(oma, ri);           // (1-a)^i
    const float sCthr   = 1.f / powi(oma, 32 - ri);// (1-a)^{i-32}

    const size_t qkbase = (size_t)b * SS * MMd;
    const size_t kTbase = (size_t)b * MMd * SS;

    for (int ch = 0; ch < 128; ++ch) {
        const int t0 = ch * 32;

        // ---- phase A: dump M0 -> Mb (bf16, swizzled); stage Vt; load Q/K frags
        #pragma unroll
        for (int tn = 0; tn < 2; ++tn)
            #pragma unroll
            for (int tm = 0; tm < 8; ++tm) {
                const int m = w * 128 + tm * 16 + l15;
                #pragma unroll
                for (int r = 0; r < 4; ++r) {
                    const int n = tn * 16 + lg * 4 + r;
                    Mb[n * 520 + (m ^ ((n & 7) << 3))] =
                        (unsigned short)f2bf(Macc[tn][tm][r]);
                }
            }
        {
            const unsigned short* vp = vg + qkbase + (size_t)(t0 + vj) * MMd + n0 + vn;
            us4 vv = *(const us4*)vp;
            #pragma unroll
            for (int c = 0; c < 4; ++c)
                Vt[(vn + c) * 40 + vj] = (unsigned short)f2bf(bf2f((short)vv[c]) * dkj);
        }
        short8 Qf[2][4], Kf[2][4];
        #pragma unroll
        for (int ti = 0; ti < 2; ++ti)
            #pragma unroll
            for (int ks = 0; ks < 4; ++ks) {
                const size_t qa = qkbase + (size_t)(t0 + ti * 16 + l15) * MMd
                                + w * 128 + ks * 32 + lg * 8;
                Qf[ti][ks] = *(const short8*)(qg + qa);
                Kf[ti][ks] = *(const short8*)(kg + qa);
            }

        // ---- phase B: S = Q.K^T partials (per-wave k-slice of 128)
        f32x4 Sacc[2][2];
        #pragma unroll
        for (int ti = 0; ti < 2; ++ti)
            #pragma unroll
            for (int tj = 0; tj < 2; ++tj) Sacc[ti][tj] = (f32x4){0.f, 0.f, 0.f, 0.f};
        #pragma unroll
        for (int ks = 0; ks < 4; ++ks)
            #pragma unroll
            for (int ti = 0; ti < 2; ++ti)
                #pragma unroll
                for (int tj = 0; tj < 2; ++tj)
                    Sacc[ti][tj] = MFMA16(Qf[ti][ks], Kf[tj][ks], Sacc[ti][tj]);

        // issue kT frag loads (latency hidden by reduce phase)
        short8 Tf[8];
        #pragma unroll
        for (int tm = 0; tm < 8; ++tm) {
            const size_t ta = kTbase + (size_t)(w * 128 + tm * 16 + l15) * SS + t0 + lg * 8;
            Tf[tm] = *(const short8*)(kTg + ta);
        }

        #pragma unroll
        for (int ti = 0; ti < 2; ++ti)
            #pragma unroll
            for (int tj = 0; tj < 2; ++tj)
                #pragma unroll
                for (int r = 0; r < 4; ++r)
                    P[w][lg * 4 + r + ti * 16][l15 + tj * 16] = Sacc[ti][tj][r];
        __syncthreads();   // B1

        // ---- phase C: reduce S, mask j<i, scale (1-a)^(i-32), -> bf16
        {
            const float4 p0 = *(const float4*)&P[0][ri][rn];
            const float4 p1 = *(const float4*)&P[1][ri][rn];
            const float4 p2 = *(const float4*)&P[2][ri][rn];
            const float4 p3 = *(const float4*)&P[3][ri][rn];
            us4 pk;
            #pragma unroll
            for (int c = 0; c < 4; ++c) {
                const int j = rn + c;
                float t = (&p0.x)[c] + (&p1.x)[c] + (&p2.x)[c] + (&p3.x)[c];
                pk[c] = (unsigned short)f2bf((j < ri) ? t * sCthr : 0.f);
            }
            *(us4*)&Sl[ri * 40 + rn] = pk;
        }
        __syncthreads();   // B2

        // ---- phase D: QM0 (raw), intra, M update
        #pragma unroll
        for (int tn = 0; tn < 2; ++tn)
            #pragma unroll
            for (int tm = 0; tm < 8; ++tm) {
                Macc[tn][tm][0] *= dC; Macc[tn][tm][1] *= dC;
                Macc[tn][tm][2] *= dC; Macc[tn][tm][3] *= dC;
            }
        short8 Vf[2];
        #pragma unroll
        for (int tn = 0; tn < 2; ++tn)
            Vf[tn] = *(const short8*)&Vt[(l15 + tn * 16) * 40 + lg * 8];

        f32x4 Racc[2][2];
        #pragma unroll
        for (int ti = 0; ti < 2; ++ti)
            #pragma unroll
            for (int tn = 0; tn < 2; ++tn) Racc[ti][tn] = (f32x4){0.f, 0.f, 0.f, 0.f};
        #pragma unroll
        for (int tnR = 0; tnR < 2; ++tnR) {
            const int n = l15 + tnR * 16;
            #pragma unroll
            for (int ks = 0; ks < 4; ++ks) {
                const int m0 = w * 128 + ks * 32 + lg * 8;
                short8 Mf8 = *(const short8*)&Mb[n * 520 + (m0 ^ ((n & 7) << 3))];
                #pragma unroll
                for (int ti = 0; ti < 2; ++ti)
                    Racc[ti][tnR] = MFMA16(Qf[ti][ks], Mf8, Racc[ti][tnR]);
            }
        }
        // intra tile (this wave owns tile (w>>1, w&1))
        f32x4 Riacc = (f32x4){0.f, 0.f, 0.f, 0.f};
        {
            const int ti = w >> 1, tj = w & 1;
            short8 Sf = *(const short8*)&Sl[(l15 + ti * 16) * 40 + lg * 8];
            Riacc = MFMA16(Sf, Vf[tj], Riacc);
        }
        // M update: Mt[n][m] += Vt^T . K  (B-frags = kT, contiguous time)
        #pragma unroll
        for (int tn = 0; tn < 2; ++tn)
            #pragma unroll
            for (int tm = 0; tm < 8; ++tm)
                Macc[tn][tm] = MFMA16(Vf[tn], Tf[tm], Macc[tn][tm]);

        #pragma unroll
        for (int ti = 0; ti < 2; ++ti)
            #pragma unroll
            for (int tn = 0; tn < 2; ++tn)
                #pragma unroll
                for (int r = 0; r < 4; ++r)
                    P[w][lg * 4 + r + ti * 16][l15 + tn * 16] = Racc[ti][tn][r];
        {
            const int ti = w >> 1, tj = w & 1;
            #pragma unroll
            for (int r = 0; r < 4; ++r)
                P2[lg * 4 + r + ti * 16][l15 + tj * 16] = Riacc[r];
        }
        __syncthreads();   // B3

        // ---- phase E: reduce R, add intra, store out
        {
            const float4 p0 = *(const float4*)&P[0][ri][rn];
            const float4 p1 = *(const float4*)&P[1][ri][rn];
            const float4 p2 = *(const float4*)&P[2][ri][rn];
            const float4 p3 = *(const float4*)&P[3][ri][rn];
            const float4 pi = *(const float4*)&P2[ri][rn];
            float4 o;
            #pragma unroll
            for (int c = 0; c < 4; ++c) {
                float t = (&p0.x)[c] + (&p1.x)[c] + (&p2.x)[c] + (&p3.x)[c];
                (&o.x)[c] = powo_ri * t + (&pi.x)[c];
            }
            *(float4*)(out + ((size_t)b * SS + t0 + ri) * MMd + n0 + rn) = o;
        }
        __syncthreads();   // B4
    }

    // final memory state
    #pragma unroll
    for (int tn = 0; tn < 2; ++tn)
        #pragma unroll
        for (int tm = 0; tm < 8; ++tm) {
            const int m = w * 128 + tm * 16 + l15;
            float4 o;
            o.x = Macc[tn][tm][0]; o.y = Macc[tn][tm][1];
            o.z = Macc[tn][tm][2]; o.w = Macc[tn][tm][3];
            *(float4*)(memf + ((size_t)b * MMd + m) * MMd + n0 + tn * 16 + lg * 4) = o;
        }
}

// ---------------------------------------------------------------------------
extern "C" void kernel_launch(void* const* d_in, const int* in_sizes, int n_in,
                              void* d_out, int out_size, void* d_ws, size_t ws_size,
                              hipStream_t stream)
{
    const float* x  = (const float*)d_in[0];
    const float* Wq = (const float*)d_in[1];
    const float* bq = (const float*)d_in[2];
    const float* Wk = (const float*)d_in[3];
    const float* bk = (const float*)d_in[4];
    const float* Wv = (const float*)d_in[5];
    const float* bv = (const float*)d_in[6];
    const float* al = (const float*)d_in[7];

    const size_t QE = (size_t)BB * SS * MMd;        // 33,554,432 elems
    unsigned short* ws = (unsigned short*)d_ws;
    unsigned short* q  = ws;
    unsigned short* k  = q + QE;
    unsigned short* v  = k + QE;
    unsigned short* kT = v + QE;
    unsigned short* wb = kT + QE;                   // 1536x1024 bf16

    // xb parked in d_out's out-region (dead until scan overwrites it)
    unsigned short* xb = (unsigned short*)d_out;    // 67.1M bf16 = 134.2MB exact
    float* out  = (float*)d_out;
    float* memf = out + QE;

    to_bf16<<<33536, 256, 0, stream>>>(x, Wq, Wk, Wv, xb, wb);
    qkv_gemm<<<6144, 256, 0, stream>>>(xb, wb, bq, bk, bv, q, k, v, kT);
    scan_mfma<<<256, 256, 0, stream>>>(q, k, v, kT, al, out, memf);
}